// Round 5
// baseline (21087.402 us; speedup 1.0000x reference)
//
#include <hip/hip_runtime.h>
#include <math.h>

// Problem constants
#define VOCAB 50000
#define EMB   1024
#define H2    512
#define R4    2048      // 4*H2 gate rows per direction
#define TLEN  4096
#define NTAGS 5
#define STARTT 3
#define STOPT  4
#define NEGV  (-10000.0f)

typedef unsigned long long u64;
typedef _Float16 half2v __attribute__((ext_vector_type(2)));

#define ALOAD64(p)    __hip_atomic_load((p), __ATOMIC_RELAXED, __HIP_MEMORY_SCOPE_AGENT)
#define ASTORE64(p,v) __hip_atomic_store((p), (v), __ATOMIC_RELAXED, __HIP_MEMORY_SCOPE_AGENT)

// Fast activations (validated exact-pass R2-R4 at bf16-level check)
__device__ __forceinline__ float fsig(float x) {
    return __builtin_amdgcn_rcpf(1.f + __expf(-x));
}
__device__ __forceinline__ float ftanh(float x) {
    return 1.f - 2.f * __builtin_amdgcn_rcpf(1.f + __expf(2.f * x));
}

// DPP butterfly add across a 16-lane row (VALU pipe, no LDS)
template <int CTRL>
__device__ __forceinline__ float dppadd(float x) {
    int o = __builtin_amdgcn_update_dpp(0, __float_as_int(x), CTRL, 0xf, 0xf, true);
    return x + __int_as_float(o);
}
#define RED16(a) do { \
    a = dppadd<0xB1>(a);   /* quad_perm xor1 */ \
    a = dppadd<0x4E>(a);   /* quad_perm xor2 */ \
    a = dppadd<0x141>(a);  /* row_half_mirror */ \
    a = dppadd<0x128>(a);  /* row_ror:8 */ \
} while (0)

// -------------------------------------------------------------------------
// Kernel 1: G[dir][t][e][gate] = Wih_dir[gate*512+e,:] . embed[sent[t],:] + biases
// [e][gate] interleave so recurrence store-lanes read one float4.
// -------------------------------------------------------------------------
__global__ __launch_bounds__(256) void input_gemm(
    const int* __restrict__ sent, const float* __restrict__ embed,
    const float* __restrict__ WihF, const float* __restrict__ WihB,
    const float* __restrict__ bihF, const float* __restrict__ bhhF,
    const float* __restrict__ bihB, const float* __restrict__ bhhB,
    float* __restrict__ G)
{
    __shared__ float As[32 * 64];
    __shared__ float Bs[32 * 64];
    const int tid = threadIdx.x;
    const int tm = blockIdx.x * 64;
    const int tn = blockIdx.y * 64;
    const int dir = blockIdx.z;
    const float* Wih = dir ? WihB : WihF;

    const int lr = tid >> 2;
    const int lp = tid & 3;
    const int srow = sent[tm + lr];
    const float* arow = embed + (size_t)srow * EMB;
    const float* brow = Wih + (size_t)(tn + lr) * EMB;

    const int mt = (tid & 15) * 4;
    const int nt = (tid >> 4) * 4;
    float acc[4][4] = {};

    for (int k0 = 0; k0 < EMB; k0 += 32) {
        float4 a0 = *(const float4*)(arow + k0 + lp * 8);
        float4 a1 = *(const float4*)(arow + k0 + lp * 8 + 4);
        float4 b0 = *(const float4*)(brow + k0 + lp * 8);
        float4 b1 = *(const float4*)(brow + k0 + lp * 8 + 4);
        __syncthreads();
        const int kb = lp * 8;
        As[(kb + 0) * 64 + lr] = a0.x; As[(kb + 1) * 64 + lr] = a0.y;
        As[(kb + 2) * 64 + lr] = a0.z; As[(kb + 3) * 64 + lr] = a0.w;
        As[(kb + 4) * 64 + lr] = a1.x; As[(kb + 5) * 64 + lr] = a1.y;
        As[(kb + 6) * 64 + lr] = a1.z; As[(kb + 7) * 64 + lr] = a1.w;
        Bs[(kb + 0) * 64 + lr] = b0.x; Bs[(kb + 1) * 64 + lr] = b0.y;
        Bs[(kb + 2) * 64 + lr] = b0.z; Bs[(kb + 3) * 64 + lr] = b0.w;
        Bs[(kb + 4) * 64 + lr] = b1.x; Bs[(kb + 5) * 64 + lr] = b1.y;
        Bs[(kb + 6) * 64 + lr] = b1.z; Bs[(kb + 7) * 64 + lr] = b1.w;
        __syncthreads();
        #pragma unroll
        for (int k = 0; k < 32; ++k) {
            float4 av = *(const float4*)(As + k * 64 + mt);
            float4 bv = *(const float4*)(Bs + k * 64 + nt);
            acc[0][0] += av.x * bv.x; acc[0][1] += av.x * bv.y; acc[0][2] += av.x * bv.z; acc[0][3] += av.x * bv.w;
            acc[1][0] += av.y * bv.x; acc[1][1] += av.y * bv.y; acc[1][2] += av.y * bv.z; acc[1][3] += av.y * bv.w;
            acc[2][0] += av.z * bv.x; acc[2][1] += av.z * bv.y; acc[2][2] += av.z * bv.z; acc[2][3] += av.z * bv.w;
            acc[3][0] += av.w * bv.x; acc[3][1] += av.w * bv.y; acc[3][2] += av.w * bv.z; acc[3][3] += av.w * bv.w;
        }
    }

    const float* bih = dir ? bihB : bihF;
    const float* bhh = dir ? bhhB : bhhF;
    float bias[4];
    #pragma unroll
    for (int jj = 0; jj < 4; ++jj)
        bias[jj] = bih[tn + nt + jj] + bhh[tn + nt + jj];
    float* Gd = G + (size_t)dir * TLEN * R4;
    #pragma unroll
    for (int ii = 0; ii < 4; ++ii) {
        #pragma unroll
        for (int jj = 0; jj < 4; ++jj) {
            int n = tn + nt + jj;
            int gate = n >> 9, ee = n & 511;
            Gd[(size_t)(tm + mt + ii) * R4 + ee * 4 + gate] = acc[ii][jj] + bias[jj];
        }
    }
}

// -------------------------------------------------------------------------
// Kernel 2: persistent BiLSTM recurrence — barrier-free, LDS-free, wave-
// autonomous. 64 WGs (dir = bx&1, w = bx>>1) x 256 thr; each wave owns 4
// h-elems. Lane (r=wl>>4, seg=wl&15): elem e = w*16+wave*4+r, cols
// seg*32..+31. Mailbox slot = u64 [tag32 | f16 h(2i+1) | f16 h(2i)],
// 256 slots/parity/dir: lanes poll their 16 slots straight into registers
// (no LDS stage, no __syncthreads -> no vmcnt(0) barrier drains).
// Safety: parity-p slot re-tagged s+3 only after ALL waves validated s+1
// on it (producer needs every wave's s+2 output first; wave-SIMD makes
// validation atomic per wave) -> re-polling safe, producer lead <= 1.
// -------------------------------------------------------------------------
__global__ __launch_bounds__(256) void lstm_rec(
    const float* __restrict__ WhhF, const float* __restrict__ WhhB,
    const float* __restrict__ h0, const float* __restrict__ c0,
    const float* __restrict__ G, float* __restrict__ hs,
    u64* hbuf)
{
    const int tid  = threadIdx.x;
    const int dir  = blockIdx.x & 1;
    const int w    = blockIdx.x >> 1;        // 0..31
    const int wave = tid >> 6;
    const int wl   = tid & 63;
    const int r    = wl >> 4;                // row in wave (elem offset 0..3)
    const int seg  = wl & 15;                // 32-col segment of h
    const int eb   = w * 16 + wave * 4;      // wave's elem base
    const int e    = eb + r;                 // this row's h-elem / gate rows
    const bool sl  = (seg == 0);             // store lane of the row

    const float* Whh = dir ? WhhB : WhhF;

    // f16 weights: W[g][k] = cols seg*32+2k, +2k+1 of row g*512+e
    half2v W[4][16];
    #pragma unroll
    for (int g = 0; g < 4; ++g) {
        const float* srcw = Whh + (size_t)(g * H2 + e) * H2 + seg * 32;
        #pragma unroll
        for (int k = 0; k < 16; ++k) {
            float2 c2 = *(const float2*)(srcw + 2 * k);
            half2v hv; hv[0] = (_Float16)c2.x; hv[1] = (_Float16)c2.y;
            W[g][k] = hv;
        }
    }

    u64* mb = hbuf + (size_t)dir * 2 * 256;  // [parity][256 slots]
    const float* Gd = G + (size_t)dir * TLEN * R4;
    float* hsd = hs + (size_t)dir * TLEN * H2;

    float cc = 0.f;
    if (sl) cc = c0[dir * H2 + e];

    // Seed parity-0 mailbox with h0 (tag 1). Lanes wl 0,32 of each wave.
    if ((wl & 31) == 0) {
        int slot = (eb >> 1) + (wl >> 5);
        half2v hp;
        hp[0] = (_Float16)h0[dir * H2 + slot * 2];
        hp[1] = (_Float16)h0[dir * H2 + slot * 2 + 1];
        ASTORE64(mb + slot, ((u64)1u << 32) | (u64)__builtin_bit_cast(unsigned, hp));
    }

    float4 gv = make_float4(0.f, 0.f, 0.f, 0.f);
    if (sl) gv = *(const float4*)(Gd + (size_t)(dir ? TLEN - 1 : 0) * R4 + e * 4);

    for (int s = 0; s < TLEN; ++s) {
        const int t = dir ? (TLEN - 1 - s) : s;
        const unsigned want = (unsigned)(s + 1);
        u64* src = mb + (s & 1) * 256 + seg * 16;

        // Pipelined poll: 16 outstanding loads, wave-wide retry
        u64 v[16];
        #pragma unroll
        for (int k = 0; k < 16; ++k) v[k] = ALOAD64(src + k);
        for (;;) {
            unsigned bad = 0;
            #pragma unroll
            for (int k = 0; k < 16; ++k) bad |= ((unsigned)(v[k] >> 32)) ^ want;
            if (bad == 0) break;
            #pragma unroll
            for (int k = 0; k < 16; ++k) v[k] = ALOAD64(src + k);
        }

        // 32-col partial dot for all 4 gates of elem e, straight from regs
        float a0 = 0.f, a1 = 0.f, a2 = 0.f, a3 = 0.f;
        #pragma unroll
        for (int k = 0; k < 16; ++k) {
            half2v x = __builtin_bit_cast(half2v, (unsigned)v[k]);
            a0 = __builtin_amdgcn_fdot2(W[0][k], x, a0, false);
            a1 = __builtin_amdgcn_fdot2(W[1][k], x, a1, false);
            a2 = __builtin_amdgcn_fdot2(W[2][k], x, a2, false);
            a3 = __builtin_amdgcn_fdot2(W[3][k], x, a3, false);
        }
        RED16(a0); RED16(a1); RED16(a2); RED16(a3);

        float hn = 0.f;
        if (sl) {
            float i_ = fsig(a0 + gv.x);
            float f_ = fsig(a1 + gv.y);
            float g_ = ftanh(a2 + gv.z);
            float o_ = fsig(a3 + gv.w);
            cc = f_ * cc + i_ * g_;
            hn = o_ * ftanh(cc);
        }
        // Pair-pack: lane 0 gets lane 16's h, lane 32 gets lane 48's
        float hpart = __shfl(hn, (wl + 16) & 63);
        if ((wl & 31) == 0) {
            int slot = (eb >> 1) + (wl >> 5);
            half2v hp; hp[0] = (_Float16)hn; hp[1] = (_Float16)hpart;
            ASTORE64(mb + ((s + 1) & 1) * 256 + slot,
                     ((u64)(unsigned)(s + 2) << 32) | (u64)__builtin_bit_cast(unsigned, hp));
        }
        if (sl) {
            hsd[(size_t)t * H2 + e] = hn;    // f32 h for feats (off critical path)
            if (s + 1 < TLEN) {
                int tn2 = dir ? (TLEN - 2 - s) : (s + 1);
                gv = *(const float4*)(Gd + (size_t)tn2 * R4 + e * 4);
            }
        }
    }
}

// -------------------------------------------------------------------------
// Kernel 3: feats[t][j] = concat(hf[t], hb[t]) . Wout[j] + bout[j]
// -------------------------------------------------------------------------
__global__ __launch_bounds__(64) void feat_kernel(
    const float* __restrict__ hs, const float* __restrict__ Wout,
    const float* __restrict__ bout, float* __restrict__ feats)
{
    const int t = blockIdx.x;
    const int lane = threadIdx.x;
    const float* hf = hs + (size_t)t * H2;
    const float* hb = hs + (size_t)TLEN * H2 + (size_t)t * H2;
    float x[16];
    #pragma unroll
    for (int r = 0; r < 8; ++r) x[r] = hf[lane + r * 64];
    #pragma unroll
    for (int r = 0; r < 8; ++r) x[8 + r] = hb[lane + r * 64];
    for (int j = 0; j < NTAGS; ++j) {
        const float* wr = Wout + (size_t)j * EMB;
        float p = 0.f;
        #pragma unroll
        for (int r = 0; r < 8; ++r) p += x[r] * wr[lane + r * 64];
        #pragma unroll
        for (int r = 0; r < 8; ++r) p += x[8 + r] * wr[H2 + lane + r * 64];
        #pragma unroll
        for (int off = 32; off > 0; off >>= 1) p += __shfl_down(p, off);
        if (lane == 0) feats[t * NTAGS + j] = p + bout[j];
    }
}

// -------------------------------------------------------------------------
// Kernel 4: Viterbi forward scan + backtrace, single wave.
// -------------------------------------------------------------------------
__global__ __launch_bounds__(64) void viterbi_kernel(
    const float* __restrict__ feats, const float* __restrict__ trans,
    float* __restrict__ out)
{
    __shared__ unsigned bp[TLEN];
    __shared__ float fch[256 * NTAGS];
    const int lane = threadIdx.x;
    const bool act = lane < 25;
    const int j = act ? (lane / 5) : 0;
    const int i = act ? (lane % 5) : 0;
    const int j5 = j * 5;
    const float tji = act ? trans[j * 5 + i] : -1e30f;
    float fv = (i == STARTT) ? 0.f : NEGV;

    for (int c0 = 0; c0 < TLEN; c0 += 256) {
        __syncthreads();
        for (int m = lane; m < 256 * NTAGS; m += 64) fch[m] = feats[c0 * NTAGS + m];
        __syncthreads();
        for (int tt = 0; tt < 256; ++tt) {
            float score = fv + tji;
            float v0 = __shfl(score, j5 + 0);
            float v1 = __shfl(score, j5 + 1);
            float v2 = __shfl(score, j5 + 2);
            float v3 = __shfl(score, j5 + 3);
            float v4 = __shfl(score, j5 + 4);
            float mm = v0; int mi = 0;
            if (v1 > mm) { mm = v1; mi = 1; }
            if (v2 > mm) { mm = v2; mi = 2; }
            if (v3 > mm) { mm = v3; mi = 3; }
            if (v4 > mm) { mm = v4; mi = 4; }
            float fnew = mm + fch[tt * NTAGS + j];
            unsigned word = ((unsigned)__shfl(mi, 0)  & 7u)
                          | (((unsigned)__shfl(mi, 5)  & 7u) << 3)
                          | (((unsigned)__shfl(mi, 10) & 7u) << 6)
                          | (((unsigned)__shfl(mi, 15) & 7u) << 9)
                          | (((unsigned)__shfl(mi, 20) & 7u) << 12);
            if (lane == 0) bp[c0 + tt] = word;
            fv = __shfl(fnew, i * 5);
        }
    }
    __syncthreads();

    float tstop = (lane < 5) ? trans[STOPT * 5 + lane] : -1e30f;
    float term = fv + tstop;
    float b0 = __shfl(term, 0), b1 = __shfl(term, 1), b2 = __shfl(term, 2);
    float b3 = __shfl(term, 3), b4 = __shfl(term, 4);
    float bsc = b0; int best = 0;
    if (b1 > bsc) { bsc = b1; best = 1; }
    if (b2 > bsc) { bsc = b2; best = 2; }
    if (b3 > bsc) { bsc = b3; best = 3; }
    if (b4 > bsc) { bsc = b4; best = 4; }

    if (lane == 0) {
        out[0] = bsc;
        int tag = best;
        out[TLEN] = (float)tag;
        #pragma unroll 16
        for (int t = TLEN - 1; t >= 1; --t) {
            tag = (int)((bp[t] >> (3 * tag)) & 7u);
            out[t] = (float)tag;
        }
    }
}

// -------------------------------------------------------------------------
// Launcher
// -------------------------------------------------------------------------
extern "C" void kernel_launch(void* const* d_in, const int* in_sizes, int n_in,
                              void* d_out, int out_size, void* d_ws, size_t ws_size,
                              hipStream_t stream) {
    const int*   sent  = (const int*)d_in[0];
    const float* h0    = (const float*)d_in[1];
    const float* c0    = (const float*)d_in[2];
    const float* embed = (const float*)d_in[3];
    const float* Wih_f = (const float*)d_in[4];
    const float* Whh_f = (const float*)d_in[5];
    const float* bih_f = (const float*)d_in[6];
    const float* bhh_f = (const float*)d_in[7];
    const float* Wih_b = (const float*)d_in[8];
    const float* Whh_b = (const float*)d_in[9];
    const float* bih_b = (const float*)d_in[10];
    const float* bhh_b = (const float*)d_in[11];
    const float* Wout  = (const float*)d_in[12];
    const float* bout  = (const float*)d_in[13];
    const float* trans = (const float*)d_in[14];

    char* ws = (char*)d_ws;
    float*    G     = (float*)(ws);                 // 2*4096*2048 f32 = 64 MB
    float*    hs    = (float*)(ws + 67108864);      // 2*4096*512  f32 = 16 MB
    u64*      hbuf  = (u64*)(ws + 83886080);        // 2 dirs * 2 parity * 256 u64 = 8 KB
    float*    feats = (float*)(ws + 83918848);      // 4096*5 f32

    input_gemm<<<dim3(TLEN / 64, R4 / 64, 2), 256, 0, stream>>>(
        sent, embed, Wih_f, Wih_b, bih_f, bhh_f, bih_b, bhh_b, G);
    lstm_rec<<<64, 256, 0, stream>>>(Whh_f, Whh_b, h0, c0, G, hs, hbuf);
    feat_kernel<<<TLEN, 64, 0, stream>>>(hs, Wout, bout, feats);
    viterbi_kernel<<<1, 64, 0, stream>>>(feats, trans, (float*)d_out);
}